// Round 1
// baseline (444.325 us; speedup 1.0000x reference)
//
#include <hip/hip_runtime.h>

// GetCostVolume: out shape (B=4, 2C=64, D=48, H=64, W=128) fp32
//   c <  32: out[b,c,d,h,w] = (w>=d) ? x[b,c,h,w]      : 0
//   c >= 32: out[b,c,d,h,w] = (w>=d) ? y[b,c-32,h,w-d] : 0
// Memory-bound: ~403 MB writes, ~8 MB unique reads (cache-resident).

#define CV_B 4
#define CV_C 32
#define CV_D 48
#define CV_H 64
#define CV_W 128
#define CV_W4 (CV_W / 4)
// total float4 outputs = B * 2C * D * H * W4 = 25,165,824
#define CV_TOTAL4 (CV_B * 2 * CV_C * CV_D * CV_H * CV_W4)

__global__ __launch_bounds__(256) void cost_volume_kernel(
    const float* __restrict__ x, const float* __restrict__ y,
    float4* __restrict__ out)
{
    int tid = blockIdx.x * blockDim.x + threadIdx.x;  // < 2^31, int ok
    int idx = tid;
    const int w4 = idx & (CV_W4 - 1);   // 0..31
    idx >>= 5;
    const int h = idx & (CV_H - 1);     // 0..63
    idx >>= 6;
    const int d = idx % CV_D;           // 0..47 (magic-mul div)
    idx /= CV_D;
    const int c = idx & 63;             // 0..63  (wave-uniform)
    const int b = idx >> 6;             // 0..3

    const int w0 = w4 * 4;
    float4 v;
    if (c < CV_C) {
        const float4* xr =
            (const float4*)(x + (((b * CV_C + c) * CV_H + h) * CV_W));
        const float4 xv = xr[w4];
        v.x = (w0 + 0 >= d) ? xv.x : 0.0f;
        v.y = (w0 + 1 >= d) ? xv.y : 0.0f;
        v.z = (w0 + 2 >= d) ? xv.z : 0.0f;
        v.w = (w0 + 3 >= d) ? xv.w : 0.0f;
    } else {
        const float* yr =
            y + (((b * CV_C + (c - CV_C)) * CV_H + h) * CV_W);
        v.x = (w0 + 0 >= d) ? yr[w0 + 0 - d] : 0.0f;
        v.y = (w0 + 1 >= d) ? yr[w0 + 1 - d] : 0.0f;
        v.z = (w0 + 2 >= d) ? yr[w0 + 2 - d] : 0.0f;
        v.w = (w0 + 3 >= d) ? yr[w0 + 3 - d] : 0.0f;
    }
    out[tid] = v;
}

extern "C" void kernel_launch(void* const* d_in, const int* in_sizes, int n_in,
                              void* d_out, int out_size, void* d_ws, size_t ws_size,
                              hipStream_t stream) {
    const float* x = (const float*)d_in[0];
    const float* y = (const float*)d_in[1];
    float4* out = (float4*)d_out;

    const int block = 256;
    const int grid = CV_TOTAL4 / block;  // 98,304 blocks
    cost_volume_kernel<<<grid, block, 0, stream>>>(x, y, out);
}

// Round 2
// 388.551 us; speedup vs baseline: 1.1435x; 1.1435x over previous
//
#include <hip/hip_runtime.h>

// GetCostVolume: out shape (B=4, 2C=64, D=48, H=64, W=128) fp32
//   c <  32: out[b,c,d,h,w] = (w>=d) ? x[b,c,h,w]      : 0
//   c >= 32: out[b,c,d,h,w] = (w>=d) ? y[b,c-32,h,w-d] : 0
//
// Round 1: one thread per (b,c,h,w4); d-loop in-thread (48 float4 stores).
//  - x half: load one float4, mask+store 48x.
//  - y half: sliding window via chained __shfl_up within 32-lane h-rows;
//    zero global re-reads. Clamped-shuffle lanes coincide with masked lanes.
// Store-bound: 403 MB writes, ~8 MB reads.

#define CV_DSTRIDE (64 * 32)          // per-d stride in float4 units (H*W4)

__global__ __launch_bounds__(256) void cost_volume_kernel(
    const float* __restrict__ x, const float* __restrict__ y,
    float4* __restrict__ out)
{
    const int tid = blockIdx.x * 256 + threadIdx.x;  // 524,288 total
    const int w4 = tid & 31;          // lane low 5 bits -> w4 (row-contiguous)
    const int h  = (tid >> 5) & 63;
    const int cc = (tid >> 11) & 63;  // wave-uniform
    const int b  = tid >> 17;
    const int w0 = w4 * 4;

    float4* outp = out + (((((b * 64 + cc) * 48) * 64 + h) * 32) + w4);

#define STORE_D(dv, e0, e1, e2, e3)                        \
    {                                                      \
        const int d_ = (dv);                               \
        float4 v;                                          \
        v.x = (w0 + 0 >= d_) ? (e0) : 0.0f;                \
        v.y = (w0 + 1 >= d_) ? (e1) : 0.0f;                \
        v.z = (w0 + 2 >= d_) ? (e2) : 0.0f;                \
        v.w = (w0 + 3 >= d_) ? (e3) : 0.0f;                \
        outp[d_ * CV_DSTRIDE] = v;                         \
    }

    if (cc < 32) {
        const float4 xv =
            *(const float4*)(x + ((b * 32 + cc) * 64 + h) * 128 + w0);
#pragma unroll
        for (int d = 0; d < 48; ++d) {
            STORE_D(d, xv.x, xv.y, xv.z, xv.w);
        }
    } else {
        float4 cur =
            *(const float4*)(y + ((b * 32 + (cc - 32)) * 64 + h) * 128 + w0);
#pragma unroll
        for (int q = 0; q < 12; ++q) {
            float4 prev;
            prev.x = __shfl_up(cur.x, 1, 32);
            prev.y = __shfl_up(cur.y, 1, 32);
            prev.z = __shfl_up(cur.z, 1, 32);
            prev.w = __shfl_up(cur.w, 1, 32);
            // d = 4q + r ; window[k] = (k>=r) ? cur[k-r] : prev[4+k-r]
            STORE_D(4 * q + 0, cur.x,  cur.y,  cur.z,  cur.w);
            STORE_D(4 * q + 1, prev.w, cur.x,  cur.y,  cur.z);
            STORE_D(4 * q + 2, prev.z, prev.w, cur.x,  cur.y);
            STORE_D(4 * q + 3, prev.y, prev.z, prev.w, cur.x);
            cur = prev;
        }
    }
#undef STORE_D
}

extern "C" void kernel_launch(void* const* d_in, const int* in_sizes, int n_in,
                              void* d_out, int out_size, void* d_ws, size_t ws_size,
                              hipStream_t stream) {
    const float* x = (const float*)d_in[0];
    const float* y = (const float*)d_in[1];
    float4* out = (float4*)d_out;

    const int block = 256;
    const int grid = (4 * 64 * 64 * 32) / block;  // 2048 blocks
    cost_volume_kernel<<<grid, block, 0, stream>>>(x, y, out);
}